// Round 2
// baseline (8438.392 us; speedup 1.0000x reference)
//
#include <hip/hip_runtime.h>

#define RD     128
#define TT     128
#define TLEN   16384
#define NB     8
#define NLAYER 63
#define N0SKIP 27
#define QD     256
#define PADR   136   // padded LDS row (bf16 elems): +16B kills bank conflicts
#define SROWS  192   // LDS tile rows: 192*136*2 = 52224 B -> 3 blocks/CU

typedef short bf16x8 __attribute__((ext_vector_type(8)));
typedef float f32x4  __attribute__((ext_vector_type(4)));

__device__ __forceinline__ unsigned short f2bf(float f) {
  unsigned u = __float_as_uint(f);
  u += 0x7fffu + ((u >> 16) & 1u);           // round-to-nearest-even
  return (unsigned short)(u >> 16);
}
__device__ __forceinline__ short f2bf_relu(float f) {
  f = f > 0.f ? f : 0.f;
  unsigned u = __float_as_uint(f);
  u += 0x7fffu + ((u >> 16) & 1u);
  return (short)(u >> 16);
}

// ---------------------------------------------------------------------------
// 128x(64c x 64t) MFMA GEMM: acc[ct][tt] += W[c][i] * H[i][t]
// W: bf16 global [128 c][128 i] row-major (A-frag = 16B contiguous load)
// H: LDS [t][i] bf16, rows padded to PADR
// ---------------------------------------------------------------------------
__device__ __forceinline__ void mfma_gemm(const unsigned short* __restrict__ aw,
                                          const short* sx, int rowbase,
                                          int c0w, int t0w, int n, int q,
                                          f32x4 (&acc)[4][4]) {
#pragma unroll
  for (int ks = 0; ks < 4; ++ks) {
    const int i0 = ks * 32 + q * 8;
    bf16x8 a[4], bb[4];
#pragma unroll
    for (int ct = 0; ct < 4; ++ct)
      a[ct] = *(const bf16x8*)&aw[(size_t)(c0w + ct * 16 + n) * RD + i0];
#pragma unroll
    for (int tt = 0; tt < 4; ++tt)
      bb[tt] = *(const bf16x8*)&sx[(rowbase + t0w + tt * 16 + n) * PADR + i0];
#pragma unroll
    for (int ct = 0; ct < 4; ++ct)
#pragma unroll
      for (int tt = 0; tt < 4; ++tt)
        acc[ct][tt] = __builtin_amdgcn_mfma_f32_16x16x32_bf16(a[ct], bb[tt],
                                                              acc[ct][tt], 0, 0, 0);
  }
}

__device__ __forceinline__ void zero_acc(f32x4 (&acc)[4][4]) {
#pragma unroll
  for (int i = 0; i < 4; ++i)
#pragma unroll
    for (int j = 0; j < 4; ++j) acc[i][j] = (f32x4){0.f, 0.f, 0.f, 0.f};
}

// stage nrows of relu(x) (fp32 global [t][c]) into LDS bf16 [row][i]
// 8-deep load pipeline: issue 8 independent global loads, then cvt+write.
#define SUNROLL 8
__device__ __forceinline__ void stage_rows(short* sx, int rowbase,
                                           const float* __restrict__ xb,
                                           int tstart, int nrows, int tid) {
  const int total = nrows * 32;
  int idx = tid;
  for (; idx + 256 * (SUNROLL - 1) < total; idx += 256 * SUNROLL) {
    float4 v[SUNROLL];
#pragma unroll
    for (int u = 0; u < SUNROLL; ++u) {
      const int i2 = idx + u * 256;
      const int tg = tstart + (i2 >> 5);
      const int c4 = (i2 & 31) << 2;
      v[u] = make_float4(0.f, 0.f, 0.f, 0.f);
      if ((unsigned)tg < (unsigned)TLEN)
        v[u] = *(const float4*)&xb[(size_t)tg * RD + c4];
    }
#pragma unroll
    for (int u = 0; u < SUNROLL; ++u) {
      const int i2 = idx + u * 256;
      const int r = i2 >> 5;
      const int c4 = (i2 & 31) << 2;
      short4 o;
      o.x = f2bf_relu(v[u].x); o.y = f2bf_relu(v[u].y);
      o.z = f2bf_relu(v[u].z); o.w = f2bf_relu(v[u].w);
      *(short4*)&sx[(rowbase + r) * PADR + c4] = o;
    }
  }
  for (; idx < total; idx += 256) {
    const int tg = tstart + (idx >> 5);
    const int c4 = (idx & 31) << 2;
    float4 v = make_float4(0.f, 0.f, 0.f, 0.f);
    if ((unsigned)tg < (unsigned)TLEN)
      v = *(const float4*)&xb[(size_t)tg * RD + c4];
    short4 o;
    o.x = f2bf_relu(v.x); o.y = f2bf_relu(v.y);
    o.z = f2bf_relu(v.z); o.w = f2bf_relu(v.w);
    *(short4*)&sx[(rowbase + (idx >> 5)) * PADR + c4] = o;
  }
}

// relu(acc + bias) -> LDS bf16 [t][c] (D layout: c = q*4+reg, t = n)
__device__ __forceinline__ void store_act_bf16(short* dst, const f32x4 (&acc)[4][4],
                                               const float* __restrict__ bias,
                                               int c0w, int t0w, int n, int q) {
#pragma unroll
  for (int ct = 0; ct < 4; ++ct) {
    const int c = c0w + ct * 16 + q * 4;
    const float4 bb = *(const float4*)&bias[c];
#pragma unroll
    for (int tt = 0; tt < 4; ++tt) {
      const int t = t0w + tt * 16 + n;
      const f32x4 A = acc[ct][tt];
      short4 o;
      o.x = f2bf_relu(A[0] + bb.x);
      o.y = f2bf_relu(A[1] + bb.y);
      o.z = f2bf_relu(A[2] + bb.z);
      o.w = f2bf_relu(A[3] + bb.w);
      *(short4*)&dst[t * PADR + c] = o;
    }
  }
}

// dst[t][c] = src[t][c] + acc + bias   (fp32 global tiles, [T][C] layout)
__device__ __forceinline__ void epi_accum(float* __restrict__ dst,
                                          const float* __restrict__ src,
                                          const float* __restrict__ bias,
                                          const f32x4 (&acc)[4][4],
                                          int c0w, int t0w, int n, int q) {
#pragma unroll
  for (int ct = 0; ct < 4; ++ct) {
    const int c = c0w + ct * 16 + q * 4;
    const float4 bb = *(const float4*)&bias[c];
#pragma unroll
    for (int tt = 0; tt < 4; ++tt) {
      const int t = t0w + tt * 16 + n;
      float4 r = *(const float4*)&src[(size_t)t * RD + c];
      const f32x4 A = acc[ct][tt];
      r.x += A[0] + bb.x; r.y += A[1] + bb.y;
      r.z += A[2] + bb.z; r.w += A[3] + bb.w;
      *(float4*)&dst[(size_t)t * RD + c] = r;
    }
  }
}

// ---------------------------------------------------------------------------
// Fused WaveNet layer (bf16 MFMA). x/skip fp32 [B][T][C].
// LDS = 192 rows (52.2 KB) -> 3 blocks/CU:
//   d<=32 : halo tile, rows [t0-d, t0+128+d)
//   d==64 : ring — stage 192 rows [t0-64,t0+128), taps 0+1, then overwrite
//           rows 0..63 with [t0+128,t0+192) for tap 2 (wave-uniform rowbase:
//           64-row ring boundary aligns with the wave t-split)
//   d>=128: per-tap serial staging (3 blocks/CU covers the sync stalls)
// ---------------------------------------------------------------------------
__global__ __launch_bounds__(256, 3) void layer_kernel(
    const float* __restrict__ x_in, float* __restrict__ x_out,
    float* __restrict__ skip,
    const unsigned short* __restrict__ wconv,   // [3][128][128] bf16
    const float* __restrict__ bconv,
    const unsigned short* __restrict__ wdense, const float* __restrict__ bdense,
    const unsigned short* __restrict__ wskip,  const float* __restrict__ bskip,
    int dil, int do_skip) {
  __shared__ short sx[SROWS * PADR];           // 52224 B -> 3 blocks/CU

  const int tid = threadIdx.x;
  // XCD-contiguous swizzle: each XCD (bid%8) gets 128 consecutive t-tiles of
  // one batch, so halo reads hit that XCD's L2. 1024%8==0 -> bijective.
  const int bid = blockIdx.x;
  const int swz = (bid & 7) * 128 + (bid >> 3);
  const int b   = swz >> 7;
  const int t0  = (swz & 127) << 7;
  const int lane = tid & 63;
  const int n = lane & 15, q = lane >> 4;
  const int w = tid >> 6;
  const int c0w = (w & 1) * 64, t0w = (w >> 1) * 64;
  const float* xb = x_in + (size_t)b * TLEN * RD;

  f32x4 acc[4][4];
  zero_acc(acc);

  if (dil <= 32) {
    // haloed tile: rows [t0-d, t0+128+d), tap k reads row t + k*d
    stage_rows(sx, 0, xb, t0 - dil, 128 + 2 * dil, tid);
    __syncthreads();
    for (int k = 0; k < 3; ++k)
      mfma_gemm(wconv + (size_t)k * RD * RD, sx, k * dil, c0w, t0w, n, q, acc);
  } else if (dil == 64) {
    stage_rows(sx, 0, xb, t0 - 64, 192, tid);
    __syncthreads();
    mfma_gemm(wconv, sx, 0, c0w, t0w, n, q, acc);                    // tap0: t-64
    mfma_gemm(wconv + (size_t)RD * RD, sx, 64, c0w, t0w, n, q, acc); // tap1: t
    __syncthreads();
    stage_rows(sx, 0, xb, t0 + 128, 64, tid);  // ring: rows 0..63 <- [t0+128,t0+192)
    __syncthreads();
    // tap2: t+64. t0w=0 waves read old rows 128..191; t0w=64 waves read new 0..63
    mfma_gemm(wconv + (size_t)2 * RD * RD, sx, (t0w == 0) ? 128 : -64,
              c0w, t0w, n, q, acc);
  } else {
    // d in {128, 256}: per-tap serial staging
#pragma unroll
    for (int k = 0; k < 3; ++k) {
      stage_rows(sx, 0, xb, t0 + (k - 1) * dil, 128, tid);
      __syncthreads();
      mfma_gemm(wconv + (size_t)k * RD * RD, sx, 0, c0w, t0w, n, q, acc);
      __syncthreads();
    }
  }
  __syncthreads();

  // h = relu(conv + bconv) -> LDS [t][c]
  store_act_bf16(sx, acc, bconv, c0w, t0w, n, q);
  __syncthreads();

  // dense + residual
  zero_acc(acc);
  mfma_gemm(wdense, sx, 0, c0w, t0w, n, q, acc);
  {
    float* xo = x_out + ((size_t)b * TLEN + t0) * RD;
    const float* xi = x_in + ((size_t)b * TLEN + t0) * RD;
    epi_accum(xo, xi, bdense, acc, c0w, t0w, n, q);
  }

  // skip accumulate
  if (do_skip) {
    zero_acc(acc);
    mfma_gemm(wskip, sx, 0, c0w, t0w, n, q, acc);
    float* sp = skip + ((size_t)b * TLEN + t0) * RD;
    epi_accum(sp, sp, bskip, acc, c0w, t0w, n, q);
  }
}

// ---------------------------------------------------------------------------
// Causal conv: x [B,1,T] -> y fp32 [B][T][C], kernel 25 pad 12
// ---------------------------------------------------------------------------
__global__ __launch_bounds__(256) void causal_kernel(const float* __restrict__ x,
                                                     const float* __restrict__ w,
                                                     const float* __restrict__ bias,
                                                     float* __restrict__ y) {
  __shared__ float xw[152];
  __shared__ float wl[RD * 25];
  __shared__ float bl[RD];
  const int tid = threadIdx.x;
  const int b   = blockIdx.x >> 7;
  const int t0  = (blockIdx.x & 127) << 7;
  for (int i = tid; i < RD * 25; i += 256) wl[i] = w[i];
  if (tid < RD) bl[tid] = bias[tid];
  for (int i = tid; i < 152; i += 256) {
    const int tg = t0 - 12 + i;
    xw[i] = ((unsigned)tg < (unsigned)TLEN) ? x[(size_t)b * TLEN + tg] : 0.f;
  }
  __syncthreads();
  const int c = tid & 127, tp = tid >> 7;
  float* yb = y + ((size_t)b * TLEN + t0) * RD + c;
  const float bc = bl[c];
  for (int i = 0; i < 64; ++i) {
    const int tl = i * 2 + tp;
    float s = bc;
#pragma unroll
    for (int k = 0; k < 25; ++k) s = fmaf(wl[c * 25 + k], xw[tl + k], s);
    yb[(size_t)tl * RD] = s;
  }
}

// ---------------------------------------------------------------------------
// Post: out[B][QD][T] = post2(relu(post1(relu(skip))))
// ---------------------------------------------------------------------------
__global__ __launch_bounds__(256, 1) void post_kernel(
    const float* __restrict__ skip,
    const unsigned short* __restrict__ p1, const float* __restrict__ p1b,
    const unsigned short* __restrict__ p2, const float* __restrict__ p2b,
    float* __restrict__ out) {
  __shared__ short sb[128 * PADR];
  __shared__ short h1[128 * PADR];
  __shared__ float ost[128 * 132];

  const int tid = threadIdx.x;
  const int b   = blockIdx.x >> 7;
  const int t0  = (blockIdx.x & 127) << 7;
  const int lane = tid & 63;
  const int n = lane & 15, q = lane >> 4;
  const int w = tid >> 6;
  const int c0w = (w & 1) * 64, t0w = (w >> 1) * 64;
  const float* skb = skip + ((size_t)b * TLEN + t0) * RD;

  for (int idx = tid; idx < 128 * 32; idx += 256) {
    const int r = idx >> 5, c4 = (idx & 31) << 2;
    float4 v = *(const float4*)&skb[(size_t)r * RD + c4];
    short4 o;
    o.x = f2bf_relu(v.x); o.y = f2bf_relu(v.y);
    o.z = f2bf_relu(v.z); o.w = f2bf_relu(v.w);
    *(short4*)&sb[r * PADR + c4] = o;
  }
  __syncthreads();

  f32x4 acc[4][4];
  zero_acc(acc);
  mfma_gemm(p1, sb, 0, c0w, t0w, n, q, acc);
  store_act_bf16(h1, acc, p1b, c0w, t0w, n, q);
  __syncthreads();

  for (int half = 0; half < 2; ++half) {
    zero_acc(acc);
    mfma_gemm(p2 + (size_t)half * RD * RD, h1, 0, c0w, t0w, n, q, acc);
#pragma unroll
    for (int ct = 0; ct < 4; ++ct) {
      const int c = c0w + ct * 16 + q * 4;
      const float4 bb = *(const float4*)&p2b[half * RD + c];
#pragma unroll
      for (int tt = 0; tt < 4; ++tt) {
        const int t = t0w + tt * 16 + n;
        const f32x4 A = acc[ct][tt];
        ost[(c + 0) * 132 + t] = A[0] + bb.x;
        ost[(c + 1) * 132 + t] = A[1] + bb.y;
        ost[(c + 2) * 132 + t] = A[2] + bb.z;
        ost[(c + 3) * 132 + t] = A[3] + bb.w;
      }
    }
    __syncthreads();
    float* ob = out + ((size_t)b * QD + half * RD) * TLEN + t0;
    for (int idx = tid; idx < 128 * 32; idx += 256) {
      const int r = idx >> 5, t4 = (idx & 31) << 2;
      const float4 v = *(const float4*)&ost[r * 132 + t4];
      *(float4*)&ob[(size_t)r * TLEN + t4] = v;
    }
    __syncthreads();
  }
}

// ---------------------------------------------------------------------------
// Weight prep: fp32 -> bf16 (+ conv relayout [L][co][ci][3] -> [L][3][co][ci])
// ---------------------------------------------------------------------------
__global__ __launch_bounds__(256) void cvt_kernel(const float* __restrict__ in,
                                                  unsigned short* __restrict__ out,
                                                  int total) {
  const int i = blockIdx.x * 256 + threadIdx.x;
  if (i < total) out[i] = f2bf(in[i]);
}
__global__ __launch_bounds__(256) void cvt_conv_kernel(const float* __restrict__ in,
                                                       unsigned short* __restrict__ out,
                                                       int total) {
  const int idx = blockIdx.x * 256 + threadIdx.x;
  if (idx >= total) return;
  const int ci = idx & 127, co = (idx >> 7) & 127, lk = idx >> 14;
  const int k = lk % 3, l = lk / 3;
  out[idx] = f2bf(in[(((size_t)l * RD + co) * RD + ci) * 3 + k]);
}

// ---------------------------------------------------------------------------
extern "C" void kernel_launch(void* const* d_in, const int* in_sizes, int n_in,
                              void* d_out, int out_size, void* d_ws, size_t ws_size,
                              hipStream_t stream) {
  const float* x        = (const float*)d_in[0];
  const float* causal_w = (const float*)d_in[1];
  const float* causal_b = (const float*)d_in[2];
  const float* dcnn_w   = (const float*)d_in[3];
  const float* dcnn_b   = (const float*)d_in[4];
  const float* dense_w  = (const float*)d_in[5];
  const float* dense_b  = (const float*)d_in[6];
  const float* skip_w   = (const float*)d_in[7];
  const float* skip_b   = (const float*)d_in[8];
  const float* post1_w  = (const float*)d_in[9];
  const float* post1_b  = (const float*)d_in[10];
  const float* post2_w  = (const float*)d_in[11];
  const float* post2_b  = (const float*)d_in[12];
  float* out = (float*)d_out;

  const size_t XN = (size_t)NB * TLEN * RD;   // 16.78M
  float* ws  = (float*)d_ws;
  float* xA  = ws;
  float* xB  = xA + XN;
  float* skp = xB + XN;
  unsigned short* wc  = (unsigned short*)(skp + XN);
  unsigned short* wd  = wc  + (size_t)NLAYER * 3 * RD * RD;
  unsigned short* wsk = wd  + (size_t)NLAYER * RD * RD;
  unsigned short* p1  = wsk + (size_t)NLAYER * RD * RD;
  unsigned short* p2  = p1  + RD * RD;

  const int tconv = NLAYER * 3 * RD * RD;
  const int t2    = NLAYER * RD * RD;
  cvt_conv_kernel<<<(tconv + 255) / 256, 256, 0, stream>>>(dcnn_w, wc, tconv);
  cvt_kernel<<<(t2 + 255) / 256, 256, 0, stream>>>(dense_w, wd, t2);
  cvt_kernel<<<(t2 + 255) / 256, 256, 0, stream>>>(skip_w, wsk, t2);
  cvt_kernel<<<(RD * RD + 255) / 256, 256, 0, stream>>>(post1_w, p1, RD * RD);
  cvt_kernel<<<(QD * RD + 255) / 256, 256, 0, stream>>>(post2_w, p2, QD * RD);

  causal_kernel<<<NB * (TLEN / TT), 256, 0, stream>>>(x, causal_w, causal_b, xA);
  hipMemsetAsync(skp, 0, XN * sizeof(float), stream);

  const float* src = xA;
  float* dst = xB;
  for (int l = 0; l < NLAYER; ++l) {
    const int dil = 1 << (l % 9);
    layer_kernel<<<NB * (TLEN / TT), 256, 0, stream>>>(
        src, dst, skp,
        wc  + (size_t)l * 3 * RD * RD, dcnn_b  + (size_t)l * RD,
        wd  + (size_t)l * RD * RD,     dense_b + (size_t)l * RD,
        wsk + (size_t)l * RD * RD,     skip_b  + (size_t)l * RD,
        dil, (l >= N0SKIP) ? 1 : 0);
    const float* tmp = src; src = dst; dst = (float*)tmp;
  }

  post_kernel<<<NB * (TLEN / TT), 256, 0, stream>>>(skp, p1, post1_b, p2, post2_b, out);
}

// Round 6
// 5100.974 us; speedup vs baseline: 1.6543x; 1.6543x over previous
//
#include <hip/hip_runtime.h>

#define RD     128
#define TT     128
#define TLEN   16384
#define NB     8
#define NLAYER 63
#define N0SKIP 27
#define QD     256
#define PADR   136   // padded LDS row (bf16 elems): +16B kills bank conflicts
#define SROWS  192   // LDS tile rows: 192*136*2 = 52224 B -> 3 blocks/CU

typedef short bf16x8 __attribute__((ext_vector_type(8)));
typedef float f32x4  __attribute__((ext_vector_type(4)));

__device__ __forceinline__ unsigned short f2bf(float f) {
  unsigned u = __float_as_uint(f);
  u += 0x7fffu + ((u >> 16) & 1u);           // round-to-nearest-even
  return (unsigned short)(u >> 16);
}
__device__ __forceinline__ short f2bf_relu(float f) {
  f = f > 0.f ? f : 0.f;
  unsigned u = __float_as_uint(f);
  u += 0x7fffu + ((u >> 16) & 1u);
  return (short)(u >> 16);
}

// ---------------------------------------------------------------------------
// 128x(64c x 64t) MFMA GEMM: acc[ct][tt] += W[c][i] * H[i][t]
// W: bf16 global [128 c][128 i] row-major (A-frag = 16B contiguous load)
// H: LDS [t][i] bf16, rows padded to PADR
// ---------------------------------------------------------------------------
__device__ __forceinline__ void mfma_gemm(const unsigned short* __restrict__ aw,
                                          const short* sx, int rowbase,
                                          int c0w, int t0w, int n, int q,
                                          f32x4 (&acc)[4][4]) {
#pragma unroll
  for (int ks = 0; ks < 4; ++ks) {
    const int i0 = ks * 32 + q * 8;
    bf16x8 a[4], bb[4];
#pragma unroll
    for (int ct = 0; ct < 4; ++ct)
      a[ct] = *(const bf16x8*)&aw[(size_t)(c0w + ct * 16 + n) * RD + i0];
#pragma unroll
    for (int tt = 0; tt < 4; ++tt)
      bb[tt] = *(const bf16x8*)&sx[(rowbase + t0w + tt * 16 + n) * PADR + i0];
#pragma unroll
    for (int ct = 0; ct < 4; ++ct)
#pragma unroll
      for (int tt = 0; tt < 4; ++tt)
        acc[ct][tt] = __builtin_amdgcn_mfma_f32_16x16x32_bf16(a[ct], bb[tt],
                                                              acc[ct][tt], 0, 0, 0);
  }
}

__device__ __forceinline__ void zero_acc(f32x4 (&acc)[4][4]) {
#pragma unroll
  for (int i = 0; i < 4; ++i)
#pragma unroll
    for (int j = 0; j < 4; ++j) acc[i][j] = (f32x4){0.f, 0.f, 0.f, 0.f};
}

// stage nrows of relu(x) (fp32 global [t][c]) into LDS bf16 [row][i]
// simple loop: register-lean (round-0/1 proven VGPR=128). Latency hiding now
// comes from 3 blocks/CU occupancy, not in-thread pipelining.
__device__ __forceinline__ void stage_rows(short* sx, int rowbase,
                                           const float* __restrict__ xb,
                                           int tstart, int nrows, int tid) {
  for (int idx = tid; idx < nrows * 32; idx += 256) {
    const int r = idx >> 5, c4 = (idx & 31) << 2;
    const int tg = tstart + r;
    float4 v = make_float4(0.f, 0.f, 0.f, 0.f);
    if ((unsigned)tg < (unsigned)TLEN)
      v = *(const float4*)&xb[(size_t)tg * RD + c4];
    short4 o;
    o.x = f2bf_relu(v.x); o.y = f2bf_relu(v.y);
    o.z = f2bf_relu(v.z); o.w = f2bf_relu(v.w);
    *(short4*)&sx[(rowbase + r) * PADR + c4] = o;
  }
}

// relu(acc + bias) -> LDS bf16 [t][c] (D layout: c = q*4+reg, t = n)
__device__ __forceinline__ void store_act_bf16(short* dst, const f32x4 (&acc)[4][4],
                                               const float* __restrict__ bias,
                                               int c0w, int t0w, int n, int q) {
#pragma unroll
  for (int ct = 0; ct < 4; ++ct) {
    const int c = c0w + ct * 16 + q * 4;
    const float4 bb = *(const float4*)&bias[c];
#pragma unroll
    for (int tt = 0; tt < 4; ++tt) {
      const int t = t0w + tt * 16 + n;
      const f32x4 A = acc[ct][tt];
      short4 o;
      o.x = f2bf_relu(A[0] + bb.x);
      o.y = f2bf_relu(A[1] + bb.y);
      o.z = f2bf_relu(A[2] + bb.z);
      o.w = f2bf_relu(A[3] + bb.w);
      *(short4*)&dst[t * PADR + c] = o;
    }
  }
}

// dst[t][c] = src[t][c] + acc + bias   (fp32 global tiles, [T][C] layout)
__device__ __forceinline__ void epi_accum(float* __restrict__ dst,
                                          const float* __restrict__ src,
                                          const float* __restrict__ bias,
                                          const f32x4 (&acc)[4][4],
                                          int c0w, int t0w, int n, int q) {
#pragma unroll
  for (int ct = 0; ct < 4; ++ct) {
    const int c = c0w + ct * 16 + q * 4;
    const float4 bb = *(const float4*)&bias[c];
#pragma unroll
    for (int tt = 0; tt < 4; ++tt) {
      const int t = t0w + tt * 16 + n;
      float4 r = *(const float4*)&src[(size_t)t * RD + c];
      const f32x4 A = acc[ct][tt];
      r.x += A[0] + bb.x; r.y += A[1] + bb.y;
      r.z += A[2] + bb.z; r.w += A[3] + bb.w;
      *(float4*)&dst[(size_t)t * RD + c] = r;
    }
  }
}

// ---------------------------------------------------------------------------
// Fused WaveNet layer (bf16 MFMA). x/skip fp32 [B][T][C].
// LDS = 192 rows (52.2 KB) -> 3 blocks/CU (needs VGPR <= 170; verify =~128):
//   d<=32 : halo tile, rows [t0-d, t0+128+d)
//   d==64 : ring — stage 192 rows [t0-64,t0+128), taps 0+1, then overwrite
//           rows 0..63 with [t0+128,t0+192) for tap 2 (wave-uniform rowbase:
//           64-row ring boundary aligns with the wave t-split)  [R2-verified]
//   d>=128: per-tap serial staging (cross-block overlap at 3 blocks/CU)
// ---------------------------------------------------------------------------
__global__ __launch_bounds__(256, 2) void layer_kernel(
    const float* __restrict__ x_in, float* __restrict__ x_out,
    float* __restrict__ skip,
    const unsigned short* __restrict__ wconv,   // [3][128][128] bf16
    const float* __restrict__ bconv,
    const unsigned short* __restrict__ wdense, const float* __restrict__ bdense,
    const unsigned short* __restrict__ wskip,  const float* __restrict__ bskip,
    int dil, int do_skip) {
  __shared__ short sx[SROWS * PADR];           // 52224 B

  const int tid = threadIdx.x;
  // XCD-contiguous swizzle: each XCD (bid%8) gets 128 consecutive t-tiles of
  // one batch, so halo reads hit that XCD's L2. 1024%8==0 -> bijective.
  const int bid = blockIdx.x;
  const int swz = (bid & 7) * 128 + (bid >> 3);
  const int b   = swz >> 7;
  const int t0  = (swz & 127) << 7;
  const int lane = tid & 63;
  const int n = lane & 15, q = lane >> 4;
  const int w = tid >> 6;
  const int c0w = (w & 1) * 64, t0w = (w >> 1) * 64;
  const float* xb = x_in + (size_t)b * TLEN * RD;

  f32x4 acc[4][4];
  zero_acc(acc);

  if (dil <= 32) {
    // haloed tile: rows [t0-d, t0+128+d), tap k reads row t + k*d
    stage_rows(sx, 0, xb, t0 - dil, 128 + 2 * dil, tid);
    __syncthreads();
    for (int k = 0; k < 3; ++k)
      mfma_gemm(wconv + (size_t)k * RD * RD, sx, k * dil, c0w, t0w, n, q, acc);
  } else if (dil == 64) {
    stage_rows(sx, 0, xb, t0 - 64, 192, tid);
    __syncthreads();
    mfma_gemm(wconv, sx, 0, c0w, t0w, n, q, acc);                    // tap0: t-64
    mfma_gemm(wconv + (size_t)RD * RD, sx, 64, c0w, t0w, n, q, acc); // tap1: t
    __syncthreads();
    stage_rows(sx, 0, xb, t0 + 128, 64, tid);  // ring: rows 0..63 <- [t0+128,t0+192)
    __syncthreads();
    // tap2: t+64. t0w=0 waves read old rows 128..191; t0w=64 waves read new 0..63
    mfma_gemm(wconv + (size_t)2 * RD * RD, sx, (t0w == 0) ? 128 : -64,
              c0w, t0w, n, q, acc);
  } else {
    // d in {128, 256}: per-tap serial staging
#pragma unroll
    for (int k = 0; k < 3; ++k) {
      stage_rows(sx, 0, xb, t0 + (k - 1) * dil, 128, tid);
      __syncthreads();
      mfma_gemm(wconv + (size_t)k * RD * RD, sx, 0, c0w, t0w, n, q, acc);
      __syncthreads();
    }
  }
  __syncthreads();

  // h = relu(conv + bconv) -> LDS [t][c]
  store_act_bf16(sx, acc, bconv, c0w, t0w, n, q);
  __syncthreads();

  // dense + residual
  zero_acc(acc);
  mfma_gemm(wdense, sx, 0, c0w, t0w, n, q, acc);
  {
    float* xo = x_out + ((size_t)b * TLEN + t0) * RD;
    const float* xi = x_in + ((size_t)b * TLEN + t0) * RD;
    epi_accum(xo, xi, bdense, acc, c0w, t0w, n, q);
  }

  // skip accumulate
  if (do_skip) {
    zero_acc(acc);
    mfma_gemm(wskip, sx, 0, c0w, t0w, n, q, acc);
    float* sp = skip + ((size_t)b * TLEN + t0) * RD;
    epi_accum(sp, sp, bskip, acc, c0w, t0w, n, q);
  }
}

// ---------------------------------------------------------------------------
// Causal conv: x [B,1,T] -> y fp32 [B][T][C], kernel 25 pad 12
// ---------------------------------------------------------------------------
__global__ __launch_bounds__(256) void causal_kernel(const float* __restrict__ x,
                                                     const float* __restrict__ w,
                                                     const float* __restrict__ bias,
                                                     float* __restrict__ y) {
  __shared__ float xw[152];
  __shared__ float wl[RD * 25];
  __shared__ float bl[RD];
  const int tid = threadIdx.x;
  const int b   = blockIdx.x >> 7;
  const int t0  = (blockIdx.x & 127) << 7;
  for (int i = tid; i < RD * 25; i += 256) wl[i] = w[i];
  if (tid < RD) bl[tid] = bias[tid];
  for (int i = tid; i < 152; i += 256) {
    const int tg = t0 - 12 + i;
    xw[i] = ((unsigned)tg < (unsigned)TLEN) ? x[(size_t)b * TLEN + tg] : 0.f;
  }
  __syncthreads();
  const int c = tid & 127, tp = tid >> 7;
  float* yb = y + ((size_t)b * TLEN + t0) * RD + c;
  const float bc = bl[c];
  for (int i = 0; i < 64; ++i) {
    const int tl = i * 2 + tp;
    float s = bc;
#pragma unroll
    for (int k = 0; k < 25; ++k) s = fmaf(wl[c * 25 + k], xw[tl + k], s);
    yb[(size_t)tl * RD] = s;
  }
}

// ---------------------------------------------------------------------------
// Post: out[B][QD][T] = post2(relu(post1(relu(skip))))
// ---------------------------------------------------------------------------
__global__ __launch_bounds__(256, 1) void post_kernel(
    const float* __restrict__ skip,
    const unsigned short* __restrict__ p1, const float* __restrict__ p1b,
    const unsigned short* __restrict__ p2, const float* __restrict__ p2b,
    float* __restrict__ out) {
  __shared__ short sb[128 * PADR];
  __shared__ short h1[128 * PADR];
  __shared__ float ost[128 * 132];

  const int tid = threadIdx.x;
  const int b   = blockIdx.x >> 7;
  const int t0  = (blockIdx.x & 127) << 7;
  const int lane = tid & 63;
  const int n = lane & 15, q = lane >> 4;
  const int w = tid >> 6;
  const int c0w = (w & 1) * 64, t0w = (w >> 1) * 64;
  const float* skb = skip + ((size_t)b * TLEN + t0) * RD;

  for (int idx = tid; idx < 128 * 32; idx += 256) {
    const int r = idx >> 5, c4 = (idx & 31) << 2;
    float4 v = *(const float4*)&skb[(size_t)r * RD + c4];
    short4 o;
    o.x = f2bf_relu(v.x); o.y = f2bf_relu(v.y);
    o.z = f2bf_relu(v.z); o.w = f2bf_relu(v.w);
    *(short4*)&sb[r * PADR + c4] = o;
  }
  __syncthreads();

  f32x4 acc[4][4];
  zero_acc(acc);
  mfma_gemm(p1, sb, 0, c0w, t0w, n, q, acc);
  store_act_bf16(h1, acc, p1b, c0w, t0w, n, q);
  __syncthreads();

  for (int half = 0; half < 2; ++half) {
    zero_acc(acc);
    mfma_gemm(p2 + (size_t)half * RD * RD, h1, 0, c0w, t0w, n, q, acc);
#pragma unroll
    for (int ct = 0; ct < 4; ++ct) {
      const int c = c0w + ct * 16 + q * 4;
      const float4 bb = *(const float4*)&p2b[half * RD + c];
#pragma unroll
      for (int tt = 0; tt < 4; ++tt) {
        const int t = t0w + tt * 16 + n;
        const f32x4 A = acc[ct][tt];
        ost[(c + 0) * 132 + t] = A[0] + bb.x;
        ost[(c + 1) * 132 + t] = A[1] + bb.y;
        ost[(c + 2) * 132 + t] = A[2] + bb.z;
        ost[(c + 3) * 132 + t] = A[3] + bb.w;
      }
    }
    __syncthreads();
    float* ob = out + ((size_t)b * QD + half * RD) * TLEN + t0;
    for (int idx = tid; idx < 128 * 32; idx += 256) {
      const int r = idx >> 5, t4 = (idx & 31) << 2;
      const float4 v = *(const float4*)&ost[r * 132 + t4];
      *(float4*)&ob[(size_t)r * TLEN + t4] = v;
    }
    __syncthreads();
  }
}

// ---------------------------------------------------------------------------
// Weight prep: fp32 -> bf16 (+ conv relayout [L][co][ci][3] -> [L][3][co][ci])
// ---------------------------------------------------------------------------
__global__ __launch_bounds__(256) void cvt_kernel(const float* __restrict__ in,
                                                  unsigned short* __restrict__ out,
                                                  int total) {
  const int i = blockIdx.x * 256 + threadIdx.x;
  if (i < total) out[i] = f2bf(in[i]);
}
__global__ __launch_bounds__(256) void cvt_conv_kernel(const float* __restrict__ in,
                                                       unsigned short* __restrict__ out,
                                                       int total) {
  const int idx = blockIdx.x * 256 + threadIdx.x;
  if (idx >= total) return;
  const int ci = idx & 127, co = (idx >> 7) & 127, lk = idx >> 14;
  const int k = lk % 3, l = lk / 3;
  out[idx] = f2bf(in[(((size_t)l * RD + co) * RD + ci) * 3 + k]);
}

// ---------------------------------------------------------------------------
extern "C" void kernel_launch(void* const* d_in, const int* in_sizes, int n_in,
                              void* d_out, int out_size, void* d_ws, size_t ws_size,
                              hipStream_t stream) {
  const float* x        = (const float*)d_in[0];
  const float* causal_w = (const float*)d_in[1];
  const float* causal_b = (const float*)d_in[2];
  const float* dcnn_w   = (const float*)d_in[3];
  const float* dcnn_b   = (const float*)d_in[4];
  const float* dense_w  = (const float*)d_in[5];
  const float* dense_b  = (const float*)d_in[6];
  const float* skip_w   = (const float*)d_in[7];
  const float* skip_b   = (const float*)d_in[8];
  const float* post1_w  = (const float*)d_in[9];
  const float* post1_b  = (const float*)d_in[10];
  const float* post2_w  = (const float*)d_in[11];
  const float* post2_b  = (const float*)d_in[12];
  float* out = (float*)d_out;

  const size_t XN = (size_t)NB * TLEN * RD;   // 16.78M
  float* ws  = (float*)d_ws;
  float* xA  = ws;
  float* xB  = xA + XN;
  float* skp = xB + XN;
  unsigned short* wc  = (unsigned short*)(skp + XN);
  unsigned short* wd  = wc  + (size_t)NLAYER * 3 * RD * RD;
  unsigned short* wsk = wd  + (size_t)NLAYER * RD * RD;
  unsigned short* p1  = wsk + (size_t)NLAYER * RD * RD;
  unsigned short* p2  = p1  + RD * RD;

  const int tconv = NLAYER * 3 * RD * RD;
  const int t2    = NLAYER * RD * RD;
  cvt_conv_kernel<<<(tconv + 255) / 256, 256, 0, stream>>>(dcnn_w, wc, tconv);
  cvt_kernel<<<(t2 + 255) / 256, 256, 0, stream>>>(dense_w, wd, t2);
  cvt_kernel<<<(t2 + 255) / 256, 256, 0, stream>>>(skip_w, wsk, t2);
  cvt_kernel<<<(RD * RD + 255) / 256, 256, 0, stream>>>(post1_w, p1, RD * RD);
  cvt_kernel<<<(QD * RD + 255) / 256, 256, 0, stream>>>(post2_w, p2, QD * RD);

  causal_kernel<<<NB * (TLEN / TT), 256, 0, stream>>>(x, causal_w, causal_b, xA);
  hipMemsetAsync(skp, 0, XN * sizeof(float), stream);

  const float* src = xA;
  float* dst = xB;
  for (int l = 0; l < NLAYER; ++l) {
    const int dil = 1 << (l % 9);
    layer_kernel<<<NB * (TLEN / TT), 256, 0, stream>>>(
        src, dst, skp,
        wc  + (size_t)l * 3 * RD * RD, dcnn_b  + (size_t)l * RD,
        wd  + (size_t)l * RD * RD,     dense_b + (size_t)l * RD,
        wsk + (size_t)l * RD * RD,     skip_b  + (size_t)l * RD,
        dil, (l >= N0SKIP) ? 1 : 0);
    const float* tmp = src; src = dst; dst = (float*)tmp;
  }

  post_kernel<<<NB * (TLEN / TT), 256, 0, stream>>>(skp, p1, post1_b, p2, post2_b, out);
}

// Round 12
// 4824.197 us; speedup vs baseline: 1.7492x; 1.0574x over previous
//
#include <hip/hip_runtime.h>

#define RD     128
#define TT     128
#define TLEN   16384
#define NB     8
#define NLAYER 63
#define N0SKIP 27
#define QD     256
#define PADR   136   // padded LDS row (bf16 elems): +16B kills bank conflicts
#define SROWS  192   // LDS tile rows: 192*136*2 = 52224 B

typedef short bf16x8 __attribute__((ext_vector_type(8)));
typedef float f32x4  __attribute__((ext_vector_type(4)));

__device__ __forceinline__ unsigned short f2bf(float f) {
  unsigned u = __float_as_uint(f);
  u += 0x7fffu + ((u >> 16) & 1u);           // round-to-nearest-even
  return (unsigned short)(u >> 16);
}
__device__ __forceinline__ short f2bf_relu(float f) {
  f = f > 0.f ? f : 0.f;
  unsigned u = __float_as_uint(f);
  u += 0x7fffu + ((u >> 16) & 1u);
  return (short)(u >> 16);
}

// ---------------------------------------------------------------------------
// 128x(64c x 64t) MFMA GEMM: acc[ct][tt] += W[c][i] * H[i][t]
// W: bf16 global [128 c][128 i] row-major (A-frag = 16B contiguous load)
// H: LDS [t][i] bf16, rows padded to PADR
// ---------------------------------------------------------------------------
__device__ __forceinline__ void mfma_gemm(const unsigned short* __restrict__ aw,
                                          const short* sx, int rowbase,
                                          int c0w, int t0w, int n, int q,
                                          f32x4 (&acc)[4][4]) {
#pragma unroll
  for (int ks = 0; ks < 4; ++ks) {
    const int i0 = ks * 32 + q * 8;
    bf16x8 a[4], bb[4];
#pragma unroll
    for (int ct = 0; ct < 4; ++ct)
      a[ct] = *(const bf16x8*)&aw[(size_t)(c0w + ct * 16 + n) * RD + i0];
#pragma unroll
    for (int tt = 0; tt < 4; ++tt)
      bb[tt] = *(const bf16x8*)&sx[(rowbase + t0w + tt * 16 + n) * PADR + i0];
#pragma unroll
    for (int ct = 0; ct < 4; ++ct)
#pragma unroll
      for (int tt = 0; tt < 4; ++tt)
        acc[ct][tt] = __builtin_amdgcn_mfma_f32_16x16x32_bf16(a[ct], bb[tt],
                                                              acc[ct][tt], 0, 0, 0);
  }
}

__device__ __forceinline__ void zero_acc(f32x4 (&acc)[4][4]) {
#pragma unroll
  for (int i = 0; i < 4; ++i)
#pragma unroll
    for (int j = 0; j < 4; ++j) acc[i][j] = (f32x4){0.f, 0.f, 0.f, 0.f};
}

// stage nrows of relu(x) (fp32 global [t][c]) into LDS bf16 [row][i].
// 8-deep load pipeline (Little's law: ~2 loads in flight -> ~2.5 TB/s ceiling
// matched R6's measured 2.45; 8 in flight lifts the staging-phase BW).
// 32 VGPR of batch state — safe under __launch_bounds__(256,2) (cap 256).
// R2's spill was the bounds-3 cap (84 VGPR alloc), not this unroll.
#define SUNROLL 8
__device__ __forceinline__ void stage_rows(short* sx, int rowbase,
                                           const float* __restrict__ xb,
                                           int tstart, int nrows, int tid) {
  const int total = nrows * 32;
  int idx = tid;
  for (; idx + 256 * (SUNROLL - 1) < total; idx += 256 * SUNROLL) {
    float4 v[SUNROLL];
#pragma unroll
    for (int u = 0; u < SUNROLL; ++u) {
      const int i2 = idx + u * 256;
      const int tg = tstart + (i2 >> 5);
      const int c4 = (i2 & 31) << 2;
      v[u] = make_float4(0.f, 0.f, 0.f, 0.f);
      if ((unsigned)tg < (unsigned)TLEN)
        v[u] = *(const float4*)&xb[(size_t)tg * RD + c4];
    }
#pragma unroll
    for (int u = 0; u < SUNROLL; ++u) {
      const int i2 = idx + u * 256;
      const int r = i2 >> 5;
      const int c4 = (i2 & 31) << 2;
      short4 o;
      o.x = f2bf_relu(v[u].x); o.y = f2bf_relu(v[u].y);
      o.z = f2bf_relu(v[u].z); o.w = f2bf_relu(v[u].w);
      *(short4*)&sx[(rowbase + r) * PADR + c4] = o;
    }
  }
  for (; idx < total; idx += 256) {
    const int tg = tstart + (idx >> 5);
    const int c4 = (idx & 31) << 2;
    float4 v = make_float4(0.f, 0.f, 0.f, 0.f);
    if ((unsigned)tg < (unsigned)TLEN)
      v = *(const float4*)&xb[(size_t)tg * RD + c4];
    short4 o;
    o.x = f2bf_relu(v.x); o.y = f2bf_relu(v.y);
    o.z = f2bf_relu(v.z); o.w = f2bf_relu(v.w);
    *(short4*)&sx[(rowbase + (idx >> 5)) * PADR + c4] = o;
  }
}

// relu(acc + bias) -> LDS bf16 [t][c] (D layout: c = q*4+reg, t = n)
__device__ __forceinline__ void store_act_bf16(short* dst, const f32x4 (&acc)[4][4],
                                               const float* __restrict__ bias,
                                               int c0w, int t0w, int n, int q) {
#pragma unroll
  for (int ct = 0; ct < 4; ++ct) {
    const int c = c0w + ct * 16 + q * 4;
    const float4 bb = *(const float4*)&bias[c];
#pragma unroll
    for (int tt = 0; tt < 4; ++tt) {
      const int t = t0w + tt * 16 + n;
      const f32x4 A = acc[ct][tt];
      short4 o;
      o.x = f2bf_relu(A[0] + bb.x);
      o.y = f2bf_relu(A[1] + bb.y);
      o.z = f2bf_relu(A[2] + bb.z);
      o.w = f2bf_relu(A[3] + bb.w);
      *(short4*)&dst[t * PADR + c] = o;
    }
  }
}

// dst[t][c] = src[t][c] + acc + bias   (fp32 global tiles, [T][C] layout)
__device__ __forceinline__ void epi_accum(float* __restrict__ dst,
                                          const float* __restrict__ src,
                                          const float* __restrict__ bias,
                                          const f32x4 (&acc)[4][4],
                                          int c0w, int t0w, int n, int q) {
#pragma unroll
  for (int ct = 0; ct < 4; ++ct) {
    const int c = c0w + ct * 16 + q * 4;
    const float4 bb = *(const float4*)&bias[c];
#pragma unroll
    for (int tt = 0; tt < 4; ++tt) {
      const int t = t0w + tt * 16 + n;
      float4 r = *(const float4*)&src[(size_t)t * RD + c];
      const f32x4 A = acc[ct][tt];
      r.x += A[0] + bb.x; r.y += A[1] + bb.y;
      r.z += A[2] + bb.z; r.w += A[3] + bb.w;
      *(float4*)&dst[(size_t)t * RD + c] = r;
    }
  }
}

// ---------------------------------------------------------------------------
// Fused WaveNet layer (bf16 MFMA). x/skip fp32 [B][T][C].
//   d<=32 : halo tile, rows [t0-d, t0+128+d)
//   d==64 : ring — stage 192 rows, taps 0+1, overwrite rows 0..63 for tap 2
//   d>=128: per-tap serial staging
// ---------------------------------------------------------------------------
__global__ __launch_bounds__(256, 2) void layer_kernel(
    const float* __restrict__ x_in, float* __restrict__ x_out,
    float* __restrict__ skip,
    const unsigned short* __restrict__ wconv,   // [3][128][128] bf16
    const float* __restrict__ bconv,
    const unsigned short* __restrict__ wdense, const float* __restrict__ bdense,
    const unsigned short* __restrict__ wskip,  const float* __restrict__ bskip,
    int dil, int do_skip) {
  __shared__ short sx[SROWS * PADR];           // 52224 B

  const int tid = threadIdx.x;
  // XCD-contiguous swizzle: each XCD (bid%8) gets 128 consecutive t-tiles of
  // one batch, so halo reads hit that XCD's L2. 1024%8==0 -> bijective.
  const int bid = blockIdx.x;
  const int swz = (bid & 7) * 128 + (bid >> 3);
  const int b   = swz >> 7;
  const int t0  = (swz & 127) << 7;
  const int lane = tid & 63;
  const int n = lane & 15, q = lane >> 4;
  const int w = tid >> 6;
  const int c0w = (w & 1) * 64, t0w = (w >> 1) * 64;
  const float* xb = x_in + (size_t)b * TLEN * RD;

  f32x4 acc[4][4];
  zero_acc(acc);

  if (dil <= 32) {
    // haloed tile: rows [t0-d, t0+128+d), tap k reads row t + k*d
    stage_rows(sx, 0, xb, t0 - dil, 128 + 2 * dil, tid);
    __syncthreads();
    for (int k = 0; k < 3; ++k)
      mfma_gemm(wconv + (size_t)k * RD * RD, sx, k * dil, c0w, t0w, n, q, acc);
  } else if (dil == 64) {
    stage_rows(sx, 0, xb, t0 - 64, 192, tid);
    __syncthreads();
    mfma_gemm(wconv, sx, 0, c0w, t0w, n, q, acc);                    // tap0: t-64
    mfma_gemm(wconv + (size_t)RD * RD, sx, 64, c0w, t0w, n, q, acc); // tap1: t
    __syncthreads();
    stage_rows(sx, 0, xb, t0 + 128, 64, tid);  // ring: rows 0..63 <- [t0+128,t0+192)
    __syncthreads();
    // tap2: t+64. t0w=0 waves read old rows 128..191; t0w=64 waves read new 0..63
    mfma_gemm(wconv + (size_t)2 * RD * RD, sx, (t0w == 0) ? 128 : -64,
              c0w, t0w, n, q, acc);
  } else {
    // d in {128, 256}: per-tap serial staging
#pragma unroll
    for (int k = 0; k < 3; ++k) {
      stage_rows(sx, 0, xb, t0 + (k - 1) * dil, 128, tid);
      __syncthreads();
      mfma_gemm(wconv + (size_t)k * RD * RD, sx, 0, c0w, t0w, n, q, acc);
      __syncthreads();
    }
  }
  __syncthreads();

  // h = relu(conv + bconv) -> LDS [t][c]
  store_act_bf16(sx, acc, bconv, c0w, t0w, n, q);
  __syncthreads();

  // dense + residual
  zero_acc(acc);
  mfma_gemm(wdense, sx, 0, c0w, t0w, n, q, acc);
  {
    float* xo = x_out + ((size_t)b * TLEN + t0) * RD;
    const float* xi = x_in + ((size_t)b * TLEN + t0) * RD;
    epi_accum(xo, xi, bdense, acc, c0w, t0w, n, q);
  }

  // skip accumulate
  if (do_skip) {
    zero_acc(acc);
    mfma_gemm(wskip, sx, 0, c0w, t0w, n, q, acc);
    float* sp = skip + ((size_t)b * TLEN + t0) * RD;
    epi_accum(sp, sp, bskip, acc, c0w, t0w, n, q);
  }
}

// ---------------------------------------------------------------------------
// Causal conv: x [B,1,T] -> y fp32 [B][T][C], kernel 25 pad 12
// ---------------------------------------------------------------------------
__global__ __launch_bounds__(256) void causal_kernel(const float* __restrict__ x,
                                                     const float* __restrict__ w,
                                                     const float* __restrict__ bias,
                                                     float* __restrict__ y) {
  __shared__ float xw[152];
  __shared__ float wl[RD * 25];
  __shared__ float bl[RD];
  const int tid = threadIdx.x;
  const int b   = blockIdx.x >> 7;
  const int t0  = (blockIdx.x & 127) << 7;
  for (int i = tid; i < RD * 25; i += 256) wl[i] = w[i];
  if (tid < RD) bl[tid] = bias[tid];
  for (int i = tid; i < 152; i += 256) {
    const int tg = t0 - 12 + i;
    xw[i] = ((unsigned)tg < (unsigned)TLEN) ? x[(size_t)b * TLEN + tg] : 0.f;
  }
  __syncthreads();
  const int c = tid & 127, tp = tid >> 7;
  float* yb = y + ((size_t)b * TLEN + t0) * RD + c;
  const float bc = bl[c];
  for (int i = 0; i < 64; ++i) {
    const int tl = i * 2 + tp;
    float s = bc;
#pragma unroll
    for (int k = 0; k < 25; ++k) s = fmaf(wl[c * 25 + k], xw[tl + k], s);
    yb[(size_t)tl * RD] = s;
  }
}

// ---------------------------------------------------------------------------
// Post: out[B][QD][T] = post2(relu(post1(relu(skip))))
// ---------------------------------------------------------------------------
__global__ __launch_bounds__(256, 1) void post_kernel(
    const float* __restrict__ skip,
    const unsigned short* __restrict__ p1, const float* __restrict__ p1b,
    const unsigned short* __restrict__ p2, const float* __restrict__ p2b,
    float* __restrict__ out) {
  __shared__ short sb[128 * PADR];
  __shared__ short h1[128 * PADR];
  __shared__ float ost[128 * 132];

  const int tid = threadIdx.x;
  const int b   = blockIdx.x >> 7;
  const int t0  = (blockIdx.x & 127) << 7;
  const int lane = tid & 63;
  const int n = lane & 15, q = lane >> 4;
  const int w = tid >> 6;
  const int c0w = (w & 1) * 64, t0w = (w >> 1) * 64;
  const float* skb = skip + ((size_t)b * TLEN + t0) * RD;

  for (int idx = tid; idx < 128 * 32; idx += 256) {
    const int r = idx >> 5, c4 = (idx & 31) << 2;
    float4 v = *(const float4*)&skb[(size_t)r * RD + c4];
    short4 o;
    o.x = f2bf_relu(v.x); o.y = f2bf_relu(v.y);
    o.z = f2bf_relu(v.z); o.w = f2bf_relu(v.w);
    *(short4*)&sb[r * PADR + c4] = o;
  }
  __syncthreads();

  f32x4 acc[4][4];
  zero_acc(acc);
  mfma_gemm(p1, sb, 0, c0w, t0w, n, q, acc);
  store_act_bf16(h1, acc, p1b, c0w, t0w, n, q);
  __syncthreads();

  for (int half = 0; half < 2; ++half) {
    zero_acc(acc);
    mfma_gemm(p2 + (size_t)half * RD * RD, h1, 0, c0w, t0w, n, q, acc);
#pragma unroll
    for (int ct = 0; ct < 4; ++ct) {
      const int c = c0w + ct * 16 + q * 4;
      const float4 bb = *(const float4*)&p2b[half * RD + c];
#pragma unroll
      for (int tt = 0; tt < 4; ++tt) {
        const int t = t0w + tt * 16 + n;
        const f32x4 A = acc[ct][tt];
        ost[(c + 0) * 132 + t] = A[0] + bb.x;
        ost[(c + 1) * 132 + t] = A[1] + bb.y;
        ost[(c + 2) * 132 + t] = A[2] + bb.z;
        ost[(c + 3) * 132 + t] = A[3] + bb.w;
      }
    }
    __syncthreads();
    float* ob = out + ((size_t)b * QD + half * RD) * TLEN + t0;
    for (int idx = tid; idx < 128 * 32; idx += 256) {
      const int r = idx >> 5, t4 = (idx & 31) << 2;
      const float4 v = *(const float4*)&ost[r * 132 + t4];
      *(float4*)&ob[(size_t)r * TLEN + t4] = v;
    }
    __syncthreads();
  }
}

// ---------------------------------------------------------------------------
// Weight prep: fp32 -> bf16 (+ conv relayout [L][co][ci][3] -> [L][3][co][ci])
// ---------------------------------------------------------------------------
__global__ __launch_bounds__(256) void cvt_kernel(const float* __restrict__ in,
                                                  unsigned short* __restrict__ out,
                                                  int total) {
  const int i = blockIdx.x * 256 + threadIdx.x;
  if (i < total) out[i] = f2bf(in[i]);
}
__global__ __launch_bounds__(256) void cvt_conv_kernel(const float* __restrict__ in,
                                                       unsigned short* __restrict__ out,
                                                       int total) {
  const int idx = blockIdx.x * 256 + threadIdx.x;
  if (idx >= total) return;
  const int ci = idx & 127, co = (idx >> 7) & 127, lk = idx >> 14;
  const int k = lk % 3, l = lk / 3;
  out[idx] = f2bf(in[(((size_t)l * RD + co) * RD + ci) * 3 + k]);
}

// ---------------------------------------------------------------------------
extern "C" void kernel_launch(void* const* d_in, const int* in_sizes, int n_in,
                              void* d_out, int out_size, void* d_ws, size_t ws_size,
                              hipStream_t stream) {
  const float* x        = (const float*)d_in[0];
  const float* causal_w = (const float*)d_in[1];
  const float* causal_b = (const float*)d_in[2];
  const float* dcnn_w   = (const float*)d_in[3];
  const float* dcnn_b   = (const float*)d_in[4];
  const float* dense_w  = (const float*)d_in[5];
  const float* dense_b  = (const float*)d_in[6];
  const float* skip_w   = (const float*)d_in[7];
  const float* skip_b   = (const float*)d_in[8];
  const float* post1_w  = (const float*)d_in[9];
  const float* post1_b  = (const float*)d_in[10];
  const float* post2_w  = (const float*)d_in[11];
  const float* post2_b  = (const float*)d_in[12];
  float* out = (float*)d_out;

  const size_t XN = (size_t)NB * TLEN * RD;   // 16.78M
  float* ws  = (float*)d_ws;
  float* xA  = ws;
  float* xB  = xA + XN;
  float* skp = xB + XN;
  unsigned short* wc  = (unsigned short*)(skp + XN);
  unsigned short* wd  = wc  + (size_t)NLAYER * 3 * RD * RD;
  unsigned short* wsk = wd  + (size_t)NLAYER * RD * RD;
  unsigned short* p1  = wsk + (size_t)NLAYER * RD * RD;
  unsigned short* p2  = p1  + RD * RD;

  const int tconv = NLAYER * 3 * RD * RD;
  const int t2    = NLAYER * RD * RD;
  cvt_conv_kernel<<<(tconv + 255) / 256, 256, 0, stream>>>(dcnn_w, wc, tconv);
  cvt_kernel<<<(t2 + 255) / 256, 256, 0, stream>>>(dense_w, wd, t2);
  cvt_kernel<<<(t2 + 255) / 256, 256, 0, stream>>>(skip_w, wsk, t2);
  cvt_kernel<<<(RD * RD + 255) / 256, 256, 0, stream>>>(post1_w, p1, RD * RD);
  cvt_kernel<<<(QD * RD + 255) / 256, 256, 0, stream>>>(post2_w, p2, QD * RD);

  causal_kernel<<<NB * (TLEN / TT), 256, 0, stream>>>(x, causal_w, causal_b, xA);
  hipMemsetAsync(skp, 0, XN * sizeof(float), stream);

  const float* src = xA;
  float* dst = xB;
  for (int l = 0; l < NLAYER; ++l) {
    const int dil = 1 << (l % 9);
    layer_kernel<<<NB * (TLEN / TT), 256, 0, stream>>>(
        src, dst, skp,
        wc  + (size_t)l * 3 * RD * RD, dcnn_b  + (size_t)l * RD,
        wd  + (size_t)l * RD * RD,     dense_b + (size_t)l * RD,
        wsk + (size_t)l * RD * RD,     skip_b  + (size_t)l * RD,
        dil, (l >= N0SKIP) ? 1 : 0);
    const float* tmp = src; src = dst; dst = (float*)tmp;
  }

  post_kernel<<<NB * (TLEN / TT), 256, 0, stream>>>(skp, p1, post1_b, p2, post2_b, out);
}